// Round 3
// baseline (2452.093 us; speedup 1.0000x reference)
//
#include <hip/hip_runtime.h>
#include <stdint.h>

typedef unsigned short u16;
typedef __attribute__((ext_vector_type(8))) short bf16x8;
typedef __attribute__((ext_vector_type(4))) float f32x4;

#define HD 256
#define KX 320    // extended K: 64 (pad of [x|xe] or [x]) + 256
#define APAD 328  // A_lds row stride in u16 (656 B = 41*16, keeps 16B alignment)

static __device__ __forceinline__ float b2f(u16 x){
  union{float f; unsigned u;} v; v.u = ((unsigned)x)<<16; return v.f;
}
static __device__ __forceinline__ u16 f2b(float f){
  union{float f; unsigned u;} v; v.f = f;
  unsigned r = v.u + 0x7fffu + ((v.u>>16)&1u);
  return (u16)(r>>16);
}

// ---------------- zero fp32 buffer (float4 per thread) ----------------
__global__ void k_zero(float* __restrict__ p, long long n4){
  long long i = (long long)blockIdx.x*blockDim.x + threadIdx.x;
  if (i < n4) *(float4*)(p + i*4) = make_float4(0.f,0.f,0.f,0.f);
}

// ---------------- build concatenated transposed bf16 B matrices from fp32 W ----------------
// BT_bp[n][k]: k<40 -> Wi[k][n]; 40<=k<64 -> 0; k>=64 -> Wh[k-64][n]
// BT_fo[n][k]: k<35 -> Wo[k][n]; 35<=k<64 -> 0; k>=64 -> Wo[k-29][n]
__global__ void k_prep_B(const float* __restrict__ Wi, const float* __restrict__ Wh,
                         const float* __restrict__ Wo,
                         u16* __restrict__ BT_bp, u16* __restrict__ BT_fo){
  int n = blockIdx.x;
  for (int k = threadIdx.x; k < KX; k += blockDim.x){
    u16 bp = 0, fo = 0;
    if (k < 40) bp = f2b(Wi[k*HD + n]);
    else if (k >= 64) bp = f2b(Wh[(k-64)*HD + n]);
    if (k < 35) fo = f2b(Wo[k*HD + n]);
    else if (k >= 64) fo = f2b(Wo[(k-29)*HD + n]);
    BT_bp[n*KX + k] = bp;
    BT_fo[n*KX + k] = fo;
  }
}

// ---------------- node_alpha scatter: alpha32[tgt[i]] += tree_m[teid[i]] (fp32) ----------------
__global__ void k_alpha_scatter(const int* __restrict__ tgt, const int* __restrict__ teid,
                                const float* __restrict__ tree_m, float* __restrict__ alpha32, int K){
  int gw = (int)(((long long)blockIdx.x*blockDim.x + threadIdx.x)>>6);
  int l = threadIdx.x & 63;
  if (gw >= K) return;
  int v = tgt[gw];
  float4 tv = *(const float4*)(tree_m + (long long)teid[gw]*HD + l*4);
  float* dst = alpha32 + (long long)v*HD + l*4;
  atomicAdd(dst+0, tv.x);
  atomicAdd(dst+1, tv.y);
  atomicAdd(dst+2, tv.z);
  atomicAdd(dst+3, tv.w);
}

// ---------------- alpha16 = bf16(alpha32) ----------------
__global__ void k_alpha_convert(const float* __restrict__ a32, u16* __restrict__ a16, long long n4){
  long long i = (long long)blockIdx.x*blockDim.x + threadIdx.x;
  if (i >= n4) return;
  float4 a = *(const float4*)(a32 + i*4);
  ushort4 o; o.x=f2b(a.x); o.y=f2b(a.y); o.z=f2b(a.z); o.w=f2b(a.w);
  *(ushort4*)(a16 + i*4) = o;
}

// ---------------- segment pointers over sorted lg_dst ----------------
__global__ void k_segptr(const int* __restrict__ lg_dst, int L, int E, int* __restrict__ start){
  int e = blockIdx.x*256 + threadIdx.x;
  if (e > E) return;
  int lo = 0, hi = L;
  while (lo < hi){ int mid = (lo+hi)>>1; if (lg_dst[mid] < e) lo = mid+1; else hi = mid; }
  start[e] = lo;
}

// ---------------- fused MPNN GEMM: out = relu(A_ext @ BT^T (+bias)) ----------------
// mode 0: rows=edges, A=[x_src|xe|0]           (K-steps: 2)   out16=relu(msg_input)
// mode 1: rows=edges, A=[x_src|xe|0|gather+α]  (K-steps: 10)  out16=BP update
// mode 2: rows=nodes, A=[x_node|0|m+α]         (K-steps: 10)  out32=relu(...+b_o)
__global__ __launch_bounds__(256) void k_mpnn(
    const float* __restrict__ xn, const float* __restrict__ xe,
    const u16* __restrict__ msg_in, const u16* __restrict__ alpha16,
    const float* __restrict__ mbuf,
    const int* __restrict__ start, const int* __restrict__ lg_src,
    const int* __restrict__ esrc,
    const u16* __restrict__ BT, const float* __restrict__ bias,
    u16* __restrict__ out16, float* __restrict__ out32, int M, int mode)
{
  __shared__ u16 A_lds[64][APAD];   // 41,984 B
  __shared__ u16 B_lds[256][40];    // 20,480 B
  const int tid = threadIdx.x;
  const int wave = tid>>6, l = tid&63;
  const int lr = l&15, lq = l>>4;
  const long long m0 = (long long)blockIdx.x*64;
  const int nw = wave*64;

  // ---- stage A cols [0,64): per-row raw features (fp32 -> bf16)
  {
    int r = tid>>2, q = tid&3;
    long long row = m0 + r;
    bool valid = row < M;
    int srcv = 0;
    if (valid) srcv = (mode==2) ? (int)row : esrc[row];
    #pragma unroll
    for (int i=0;i<16;i++){
      int k = q*16 + i;
      u16 v = 0;
      if (valid){
        if (k < 35) v = f2b(xn[(long long)srcv*35 + k]);
        else if (k < 40 && mode != 2) v = f2b(xe[row*5 + (k-35)]);
      }
      A_lds[r][k] = v;
    }
  }
  // ---- stage A cols [64,320)
  if (mode == 1){
    // fused line-graph gather: t[e] = sum_{seg(e)} msg[lg_src] + alpha16[src[e]]
    for (int r = wave; r < 64; r += 4){
      long long row = m0 + r;
      if (row < M){
        int s = start[row], e2 = start[row+1];
        int sv = esrc[row];
        ushort4 av = *(const ushort4*)(alpha16 + (long long)sv*HD + l*4);
        float a0=b2f(av.x), a1=b2f(av.y), a2=b2f(av.z), a3=b2f(av.w);
        for (int j=s;j<e2;j++){
          int r2 = lg_src[j];
          ushort4 mv = *(const ushort4*)(msg_in + (long long)r2*HD + l*4);
          a0 += b2f(mv.x); a1 += b2f(mv.y); a2 += b2f(mv.z); a3 += b2f(mv.w);
        }
        ushort4 o; o.x=f2b(a0); o.y=f2b(a1); o.z=f2b(a2); o.w=f2b(a3);
        *(ushort4*)&A_lds[r][64 + l*4] = o;
      }
    }
  } else if (mode == 2){
    int r = tid>>2, q = tid&3;
    long long row = m0 + r;
    if (row < M){
      #pragma unroll
      for (int i=0;i<16;i++){
        int c = q*64 + i*4;
        float4 mv = *(const float4*)(mbuf + row*HD + c);
        ushort4 av = *(const ushort4*)(alpha16 + row*HD + c);
        ushort4 o;
        o.x=f2b(mv.x + b2f(av.x)); o.y=f2b(mv.y + b2f(av.y));
        o.z=f2b(mv.z + b2f(av.z)); o.w=f2b(mv.w + b2f(av.w));
        *(ushort4*)&A_lds[r][64 + c] = o;
      }
    }
  }

  const int ksteps = (mode==0) ? 2 : 10;
  f32x4 acc[4][4] = {};
  for (int ks=0; ks<ksteps; ks++){
    const int k0 = ks*32;
    {
      int nr = tid>>2, aq = tid&3;
      #pragma unroll
      for (int p=0;p<4;p++){
        int n = p*64 + nr;
        *(uint4*)&B_lds[n][aq*8] = *(const uint4*)(BT + n*KX + k0 + aq*8);
      }
    }
    __syncthreads();   // first pass also guards A staging
    bf16x8 af[4], bfr[4];
    #pragma unroll
    for (int mi=0;mi<4;mi++) af[mi] = *(const bf16x8*)&A_lds[mi*16+lr][k0 + lq*8];
    #pragma unroll
    for (int nj=0;nj<4;nj++) bfr[nj] = *(const bf16x8*)&B_lds[nw+nj*16+lr][lq*8];
    #pragma unroll
    for (int mi=0;mi<4;mi++)
      #pragma unroll
      for (int nj=0;nj<4;nj++)
        acc[mi][nj] = __builtin_amdgcn_mfma_f32_16x16x32_bf16(af[mi], bfr[nj], acc[mi][nj], 0,0,0);
    __syncthreads();
  }
  #pragma unroll
  for (int mi=0;mi<4;mi++){
    #pragma unroll
    for (int j=0;j<4;j++){
      long long gm = m0 + mi*16 + lq*4 + j;
      if (gm < M){
        #pragma unroll
        for (int nj=0;nj<4;nj++){
          int col = nw + nj*16 + lr;
          float v = acc[mi][nj][j];
          if (mode==2){
            v += bias[col];
            out32[gm*HD + col] = v > 0.f ? v : 0.f;
          } else {
            out16[gm*HD + col] = f2b(v > 0.f ? v : 0.f);
          }
        }
      }
    }
  }
}

// ---------------- m scatter: mbuf[dst[e]] += msg[e] ----------------
__global__ void k_m_scatter(const u16* __restrict__ msg, const int* __restrict__ edst,
                            float* __restrict__ m, int E){
  int w = (int)(((long long)blockIdx.x*blockDim.x + threadIdx.x)>>6);
  int l = threadIdx.x & 63;
  if (w >= E) return;
  int v = edst[w];
  ushort4 mv = *(const ushort4*)(msg + (long long)w*HD + l*4);
  float* dst = m + (long long)v*HD + l*4;
  atomicAdd(dst+0, b2f(mv.x));
  atomicAdd(dst+1, b2f(mv.y));
  atomicAdd(dst+2, b2f(mv.z));
  atomicAdd(dst+3, b2f(mv.w));
}

// ---------------- graph mean (graph_ids sorted), fp32 in/out ----------------
__global__ void k_graph_mean(const float* __restrict__ h, const int* __restrict__ gid,
                             int N, int G, float* __restrict__ out){
  int g = (int)(((long long)blockIdx.x*blockDim.x + threadIdx.x)>>6);
  int l = threadIdx.x & 63;
  if (g >= G) return;
  int lo=0, hi=N;
  while (lo<hi){ int mid=(lo+hi)>>1; if (gid[mid] < g) lo=mid+1; else hi=mid; }
  int b = lo;
  hi = N;
  while (lo<hi){ int mid=(lo+hi)>>1; if (gid[mid] < g+1) lo=mid+1; else hi=mid; }
  int e2 = lo;
  float a0=0.f,a1=0.f,a2=0.f,a3=0.f;
  for (int v=b; v<e2; v++){
    float4 hv = *(const float4*)(h + (long long)v*HD + l*4);
    a0 += hv.x; a1 += hv.y; a2 += hv.z; a3 += hv.w;
  }
  int cnt = e2 - b; if (cnt < 1) cnt = 1;
  float inv = 1.0f/(float)cnt;
  float4 o; o.x=a0*inv; o.y=a1*inv; o.z=a2*inv; o.w=a3*inv;
  *(float4*)(out + (long long)g*HD + l*4) = o;
}

extern "C" void kernel_launch(void* const* d_in, const int* in_sizes, int n_in,
                              void* d_out, int out_size, void* d_ws, size_t ws_size,
                              hipStream_t stream){
  const float* x_nodes = (const float*)d_in[0];
  const float* x_edges = (const float*)d_in[1];
  const float* tree_m  = (const float*)d_in[2];
  const float* W_i     = (const float*)d_in[3];
  const float* W_h     = (const float*)d_in[4];
  const float* W_o     = (const float*)d_in[5];
  const float* b_o     = (const float*)d_in[6];
  const int* edge_src = (const int*)d_in[7];
  const int* edge_dst = (const int*)d_in[8];
  const int* lg_src   = (const int*)d_in[9];
  const int* lg_dst   = (const int*)d_in[10];
  const int* tgt      = (const int*)d_in[11];
  const int* teid     = (const int*)d_in[12];
  const int* gid      = (const int*)d_in[13];

  const int N = in_sizes[0]/35;
  const int E = in_sizes[1]/5;
  const int L = in_sizes[9];
  const int K = in_sizes[11];
  const int G = out_size/HD;

  // ---- workspace layout (~231.5 MB total, proven to fit in round 2) ----
  char* wsb = (char*)d_ws;
  auto align256 = [](size_t x){ return (x + 255) & ~(size_t)255; };
  size_t oMsgA    = 0;
  size_t oMsgB    = oMsgA    + align256((size_t)E*HD*2);   // 102.4 MB
  size_t oAlpha16 = oMsgB    + align256((size_t)E*HD*2);   // 102.4 MB
  size_t oBTbp    = oAlpha16 + align256((size_t)N*HD*2);   // 25.6 MB
  size_t oBTfo    = oBTbp    + align256((size_t)256*KX*2); // 160 KB
  size_t oStart   = oBTfo    + align256((size_t)256*KX*2); // 160 KB

  u16*   msgA    = (u16*)(wsb + oMsgA);
  u16*   msgB    = (u16*)(wsb + oMsgB);
  u16*   alpha16 = (u16*)(wsb + oAlpha16);
  u16*   BT_bp   = (u16*)(wsb + oBTbp);
  u16*   BT_fo   = (u16*)(wsb + oBTfo);
  int*   startp  = (int*)(wsb + oStart);
  // carved from dead msg regions:
  float* alpha32 = (float*)(wsb + oMsgB);                  // dead before BP iter1 writes msgB
  float* mbuf    = (float*)(wsb + oMsgA);                  // msgA dead after BP iter3 (51.2 MB)
  float* hbuf    = (float*)(wsb + oMsgA + (size_t)N*HD*4); // next 51.2 MB (exactly fills msgA region)

  const long long NH4 = (long long)N*HD/4;
  const int zgrid = (int)((NH4 + 255)/256);

  k_zero<<<zgrid, 256, 0, stream>>>(alpha32, NH4);
  k_prep_B<<<256, 256, 0, stream>>>(W_i, W_h, W_o, BT_bp, BT_fo);
  k_alpha_scatter<<<(K+3)/4, 256, 0, stream>>>(tgt, teid, tree_m, alpha32, K);
  k_alpha_convert<<<zgrid, 256, 0, stream>>>(alpha32, alpha16, NH4);
  k_segptr<<<(E+1+255)/256, 256, 0, stream>>>(lg_dst, L, E, startp);

  const int egrid = (E+63)/64;
  // iter0: msgA = relu([x_src|xe] @ Wi)
  k_mpnn<<<egrid, 256, 0, stream>>>(x_nodes, x_edges, (const u16*)0, alpha16, (const float*)0,
                                    startp, lg_src, edge_src, BT_bp, (const float*)0,
                                    msgA, (float*)0, E, 0);
  // BP iters: A -> B -> A -> B
  k_mpnn<<<egrid, 256, 0, stream>>>(x_nodes, x_edges, msgA, alpha16, (const float*)0,
                                    startp, lg_src, edge_src, BT_bp, (const float*)0,
                                    msgB, (float*)0, E, 1);
  k_mpnn<<<egrid, 256, 0, stream>>>(x_nodes, x_edges, msgB, alpha16, (const float*)0,
                                    startp, lg_src, edge_src, BT_bp, (const float*)0,
                                    msgA, (float*)0, E, 1);
  k_mpnn<<<egrid, 256, 0, stream>>>(x_nodes, x_edges, msgA, alpha16, (const float*)0,
                                    startp, lg_src, edge_src, BT_bp, (const float*)0,
                                    msgB, (float*)0, E, 1);
  // final msg is msgB; msgA region becomes scratch (mbuf, hbuf)
  k_zero<<<zgrid, 256, 0, stream>>>(mbuf, NH4);
  k_m_scatter<<<(E+3)/4, 256, 0, stream>>>(msgB, edge_dst, mbuf, E);
  // output layer: h = relu([x_node | m+alpha] @ Wo + b_o)  (fp32 out)
  k_mpnn<<<(N+63)/64, 256, 0, stream>>>(x_nodes, (const float*)0, (const u16*)0, alpha16, mbuf,
                                        startp, lg_src, edge_src, BT_fo, b_o,
                                        (u16*)0, hbuf, N, 2);
  k_graph_mean<<<(G+3)/4, 256, 0, stream>>>(hbuf, gid, N, G, (float*)d_out);
}

// Round 4
// 1921.402 us; speedup vs baseline: 1.2762x; 1.2762x over previous
//
#include <hip/hip_runtime.h>
#include <stdint.h>

typedef unsigned short u16;
typedef __attribute__((ext_vector_type(8))) short bf16x8;
typedef __attribute__((ext_vector_type(4))) float f32x4;

#define HD 256
#define KX 320    // extended K: 64 (pad of [x|xe] or [x]) + 256
#define APAD 328  // A_lds row stride in u16 (656 B, 16B-aligned rows)

static __device__ __forceinline__ float b2f(u16 x){
  union{float f; unsigned u;} v; v.u = ((unsigned)x)<<16; return v.f;
}
static __device__ __forceinline__ u16 f2b(float f){
  union{float f; unsigned u;} v; v.f = f;
  unsigned r = v.u + 0x7fffu + ((v.u>>16)&1u);
  return (u16)(r>>16);
}

// ---------------- zero int buffer ----------------
__global__ void k_zero_int(int* __restrict__ p, int n){
  int i = blockIdx.x*256 + threadIdx.x;
  if (i < n) p[i] = 0;
}

// ---------------- histogram: deg[key[i]]++ ----------------
__global__ void k_hist(const int* __restrict__ key, int* __restrict__ deg, int n){
  int i = blockIdx.x*256 + threadIdx.x;
  if (i < n) atomicAdd(&deg[key[i]], 1);
}

// ---------------- single-block exclusive scan: deg[0..n) -> start[0..n], cursor[0..n) ----------------
__global__ __launch_bounds__(1024) void k_scan(const int* __restrict__ deg, int* __restrict__ start,
                                               int* __restrict__ cursor, int n){
  __shared__ int sm[1024];
  const int t = threadIdx.x;
  const int chunk = (n + 1023) >> 10;
  const int lo = t*chunk, hi = min(lo+chunk, n);
  int s = 0;
  for (int i=lo;i<hi;i++) s += deg[i];
  sm[t] = s;
  __syncthreads();
  for (int ofs=1; ofs<1024; ofs<<=1){
    int v = (t>=ofs) ? sm[t-ofs] : 0;
    __syncthreads();
    sm[t] += v;
    __syncthreads();
  }
  int base = sm[t] - s;   // exclusive base for this chunk
  for (int i=lo;i<hi;i++){
    start[i] = base; cursor[i] = base;
    base += deg[i];
  }
  if (t == 1023) start[n] = sm[1023];
}

// ---------------- fill buckets: pos=cursor[key[i]]++; bucket[pos]=val[i] (or i) ----------------
__global__ void k_fill(const int* __restrict__ key, const int* __restrict__ val,
                       int* __restrict__ cursor, int* __restrict__ bucket, int n){
  int i = blockIdx.x*256 + threadIdx.x;
  if (i >= n) return;
  int pos = atomicAdd(&cursor[key[i]], 1);
  bucket[pos] = val ? val[i] : i;
}

// ---------------- alpha16[v] = bf16( sum_{j in tgt-bucket(v)} tree_m[bucket[j]] ) ----------------
__global__ void k_alpha_gather(const float* __restrict__ tree_m, const int* __restrict__ start,
                               const int* __restrict__ bucket, u16* __restrict__ alpha16, int N){
  int v = (int)(((long long)blockIdx.x*blockDim.x + threadIdx.x)>>6);
  int l = threadIdx.x & 63;
  if (v >= N) return;
  int s = start[v], e2 = start[v+1];
  float a0=0.f,a1=0.f,a2=0.f,a3=0.f;
  for (int j=s;j<e2;j++){
    float4 tv = *(const float4*)(tree_m + (long long)bucket[j]*HD + l*4);
    a0 += tv.x; a1 += tv.y; a2 += tv.z; a3 += tv.w;
  }
  ushort4 o; o.x=f2b(a0); o.y=f2b(a1); o.z=f2b(a2); o.w=f2b(a3);
  *(ushort4*)(alpha16 + (long long)v*HD + l*4) = o;
}

// ---------------- build concatenated transposed bf16 B matrices from fp32 W ----------------
__global__ void k_prep_B(const float* __restrict__ Wi, const float* __restrict__ Wh,
                         const float* __restrict__ Wo,
                         u16* __restrict__ BT_bp, u16* __restrict__ BT_fo){
  int n = blockIdx.x;
  for (int k = threadIdx.x; k < KX; k += blockDim.x){
    u16 bp = 0, fo = 0;
    if (k < 40) bp = f2b(Wi[k*HD + n]);
    else if (k >= 64) bp = f2b(Wh[(k-64)*HD + n]);
    if (k < 35) fo = f2b(Wo[k*HD + n]);
    else if (k >= 64) fo = f2b(Wo[(k-29)*HD + n]);
    BT_bp[n*KX + k] = bp;
    BT_fo[n*KX + k] = fo;
  }
}

// ---------------- segment pointers over sorted lg_dst ----------------
__global__ void k_segptr(const int* __restrict__ lg_dst, int L, int E, int* __restrict__ start){
  int e = blockIdx.x*256 + threadIdx.x;
  if (e > E) return;
  int lo = 0, hi = L;
  while (lo < hi){ int mid = (lo+hi)>>1; if (lg_dst[mid] < e) lo = mid+1; else hi = mid; }
  start[e] = lo;
}

// ---------------- fused MPNN GEMM: out = relu(A_ext @ BT^T (+bias)) ----------------
// mode 0: rows=edges, A=[x_src|xe|0]              (K-steps 2)   out16 = relu(msg_input)
// mode 1: rows=edges, A=[x_src|xe|0|lg_gather+α_src] (K-steps 10) out16 = BP update
// mode 2: rows=nodes, A=[x_node|0|dst_gather+α_row]  (K-steps 10) out32 = relu(..+b_o)
__global__ __launch_bounds__(256) void k_mpnn(
    const float* __restrict__ xn, const float* __restrict__ xe,
    const u16* __restrict__ msg_in, const u16* __restrict__ alpha16,
    const int* __restrict__ seg, const int* __restrict__ keys,
    const int* __restrict__ esrc,
    const u16* __restrict__ BT, const float* __restrict__ bias,
    u16* __restrict__ out16, float* __restrict__ out32, int M, int mode)
{
  __shared__ u16 A_lds[64][APAD];   // 41,984 B
  __shared__ u16 B_lds[256][40];    // 20,480 B
  const int tid = threadIdx.x;
  const int wave = tid>>6, l = tid&63;
  const int lr = l&15, lq = l>>4;
  const long long m0 = (long long)blockIdx.x*64;
  const int nw = wave*64;

  // ---- stage A cols [0,64): per-row raw features (fp32 -> bf16)
  {
    int r = tid>>2, q = tid&3;
    long long row = m0 + r;
    bool valid = row < M;
    int srcv = 0;
    if (valid) srcv = (mode==2) ? (int)row : esrc[row];
    #pragma unroll
    for (int i=0;i<16;i++){
      int k = q*16 + i;
      u16 v = 0;
      if (valid){
        if (k < 35) v = f2b(xn[(long long)srcv*35 + k]);
        else if (k < 40 && mode != 2) v = f2b(xe[row*5 + (k-35)]);
      }
      A_lds[r][k] = v;
    }
  }
  // ---- stage A cols [64,320): fused segment gather + alpha
  if (mode >= 1){
    for (int r = wave; r < 64; r += 4){
      long long row = m0 + r;
      if (row < M){
        int s = seg[row], e2 = seg[row+1];
        int an = (mode==1) ? esrc[row] : (int)row;
        ushort4 av = *(const ushort4*)(alpha16 + (long long)an*HD + l*4);
        float a0=b2f(av.x), a1=b2f(av.y), a2=b2f(av.z), a3=b2f(av.w);
        for (int j=s;j<e2;j++){
          int r2 = keys[j];
          ushort4 mv = *(const ushort4*)(msg_in + (long long)r2*HD + l*4);
          a0 += b2f(mv.x); a1 += b2f(mv.y); a2 += b2f(mv.z); a3 += b2f(mv.w);
        }
        ushort4 o; o.x=f2b(a0); o.y=f2b(a1); o.z=f2b(a2); o.w=f2b(a3);
        *(ushort4*)&A_lds[r][64 + l*4] = o;
      }
    }
  }

  const int ksteps = (mode==0) ? 2 : 10;
  f32x4 acc[4][4] = {};
  for (int ks=0; ks<ksteps; ks++){
    const int k0 = ks*32;
    {
      int nr = tid>>2, aq = tid&3;
      #pragma unroll
      for (int p=0;p<4;p++){
        int n = p*64 + nr;
        *(uint4*)&B_lds[n][aq*8] = *(const uint4*)(BT + n*KX + k0 + aq*8);
      }
    }
    __syncthreads();   // first pass also guards A staging
    bf16x8 af[4], bfr[4];
    #pragma unroll
    for (int mi=0;mi<4;mi++) af[mi] = *(const bf16x8*)&A_lds[mi*16+lr][k0 + lq*8];
    #pragma unroll
    for (int nj=0;nj<4;nj++) bfr[nj] = *(const bf16x8*)&B_lds[nw+nj*16+lr][lq*8];
    #pragma unroll
    for (int mi=0;mi<4;mi++)
      #pragma unroll
      for (int nj=0;nj<4;nj++)
        acc[mi][nj] = __builtin_amdgcn_mfma_f32_16x16x32_bf16(af[mi], bfr[nj], acc[mi][nj], 0,0,0);
    __syncthreads();
  }
  #pragma unroll
  for (int mi=0;mi<4;mi++){
    #pragma unroll
    for (int j=0;j<4;j++){
      long long gm = m0 + mi*16 + lq*4 + j;
      if (gm < M){
        #pragma unroll
        for (int nj=0;nj<4;nj++){
          int col = nw + nj*16 + lr;
          float v = acc[mi][nj][j];
          if (mode==2){
            v += bias[col];
            out32[gm*HD + col] = v > 0.f ? v : 0.f;
          } else {
            out16[gm*HD + col] = f2b(v > 0.f ? v : 0.f);
          }
        }
      }
    }
  }
}

// ---------------- graph mean (graph_ids sorted), fp32 in/out ----------------
__global__ void k_graph_mean(const float* __restrict__ h, const int* __restrict__ gid,
                             int N, int G, float* __restrict__ out){
  int g = (int)(((long long)blockIdx.x*blockDim.x + threadIdx.x)>>6);
  int l = threadIdx.x & 63;
  if (g >= G) return;
  int lo=0, hi=N;
  while (lo<hi){ int mid=(lo+hi)>>1; if (gid[mid] < g) lo=mid+1; else hi=mid; }
  int b = lo;
  hi = N;
  while (lo<hi){ int mid=(lo+hi)>>1; if (gid[mid] < g+1) lo=mid+1; else hi=mid; }
  int e2 = lo;
  float a0=0.f,a1=0.f,a2=0.f,a3=0.f;
  for (int v=b; v<e2; v++){
    float4 hv = *(const float4*)(h + (long long)v*HD + l*4);
    a0 += hv.x; a1 += hv.y; a2 += hv.z; a3 += hv.w;
  }
  int cnt = e2 - b; if (cnt < 1) cnt = 1;
  float inv = 1.0f/(float)cnt;
  float4 o; o.x=a0*inv; o.y=a1*inv; o.z=a2*inv; o.w=a3*inv;
  *(float4*)(out + (long long)g*HD + l*4) = o;
}

extern "C" void kernel_launch(void* const* d_in, const int* in_sizes, int n_in,
                              void* d_out, int out_size, void* d_ws, size_t ws_size,
                              hipStream_t stream){
  const float* x_nodes = (const float*)d_in[0];
  const float* x_edges = (const float*)d_in[1];
  const float* tree_m  = (const float*)d_in[2];
  const float* W_i     = (const float*)d_in[3];
  const float* W_h     = (const float*)d_in[4];
  const float* W_o     = (const float*)d_in[5];
  const float* b_o     = (const float*)d_in[6];
  const int* edge_src = (const int*)d_in[7];
  const int* edge_dst = (const int*)d_in[8];
  const int* lg_src   = (const int*)d_in[9];
  const int* lg_dst   = (const int*)d_in[10];
  const int* tgt      = (const int*)d_in[11];
  const int* teid     = (const int*)d_in[12];
  const int* gid      = (const int*)d_in[13];

  const int N = in_sizes[0]/35;
  const int E = in_sizes[1]/5;
  const int L = in_sizes[9];
  const int K = in_sizes[11];
  const int G = out_size/HD;

  // ---- workspace layout (~231.5 MB total footprint, proven safe) ----
  char* wsb = (char*)d_ws;
  auto align256 = [](size_t x){ return (x + 255) & ~(size_t)255; };
  size_t oMsgA    = 0;
  size_t oMsgB    = oMsgA    + align256((size_t)E*HD*2);   // 102.4 MB
  size_t oAlpha16 = oMsgB    + align256((size_t)E*HD*2);   // 102.4 MB
  size_t oBTbp    = oAlpha16 + align256((size_t)N*HD*2);   // 25.6 MB
  size_t oBTfo    = oBTbp    + align256((size_t)256*KX*2); // 160 KB
  size_t oStart   = oBTfo    + align256((size_t)256*KX*2); // 160 KB

  u16*   msgA    = (u16*)(wsb + oMsgA);
  u16*   msgB    = (u16*)(wsb + oMsgB);
  u16*   alpha16 = (u16*)(wsb + oAlpha16);
  u16*   BT_bp   = (u16*)(wsb + oBTbp);
  u16*   BT_fo   = (u16*)(wsb + oBTfo);
  int*   startp  = (int*)(wsb + oStart);

  // tgt-CSR: lives in msgB region, fully consumed before BP iter1 writes msgB
  const size_t SLOT = 262144; // 256 KB slots (N+1 ints = 200,004 B fits)
  int* deg_t    = (int*)(wsb + oMsgB + 0*SLOT);
  int* start_t  = (int*)(wsb + oMsgB + 1*SLOT);
  int* cursor_t = (int*)(wsb + oMsgB + 2*SLOT);
  int* bucket_t = (int*)(wsb + oMsgB + 3*SLOT);            // K ints = 200 KB

  // dst-CSR + hbuf: live in msgA region, used only after BP iter3 (msgA dead)
  float* hbuf   = (float*)(wsb + oMsgA);                   // N*HD*4 = 51.2 MB
  size_t oCsrD  = oMsgA + align256((size_t)N*HD*4) + 4096;
  int* deg_d    = (int*)(wsb + oCsrD + 0*SLOT);
  int* start_d  = (int*)(wsb + oCsrD + 1*SLOT);
  int* cursor_d = (int*)(wsb + oCsrD + 2*SLOT);
  int* bucket_d = (int*)(wsb + oCsrD + 3*SLOT);            // E ints = 800 KB

  const int ngrid = (N+255)/256;
  const int egrid256 = (E+255)/256;
  const int kgrid256 = (K+255)/256;

  k_prep_B<<<256, 256, 0, stream>>>(W_i, W_h, W_o, BT_bp, BT_fo);
  k_segptr<<<(E+1+255)/256, 256, 0, stream>>>(lg_dst, L, E, startp);

  // tgt-CSR + alpha gather (before any BP write to msgB)
  k_zero_int<<<ngrid, 256, 0, stream>>>(deg_t, N);
  k_hist<<<kgrid256, 256, 0, stream>>>(tgt, deg_t, K);
  k_scan<<<1, 1024, 0, stream>>>(deg_t, start_t, cursor_t, N);
  k_fill<<<kgrid256, 256, 0, stream>>>(tgt, teid, cursor_t, bucket_t, K);
  k_alpha_gather<<<(N+3)/4, 256, 0, stream>>>(tree_m, start_t, bucket_t, alpha16, N);

  const int egrid = (E+63)/64;
  // iter0: msgA = relu([x_src|xe] @ Wi)
  k_mpnn<<<egrid, 256, 0, stream>>>(x_nodes, x_edges, (const u16*)0, alpha16,
                                    startp, lg_src, edge_src, BT_bp, (const float*)0,
                                    msgA, (float*)0, E, 0);
  // BP iters: A -> B -> A -> B
  k_mpnn<<<egrid, 256, 0, stream>>>(x_nodes, x_edges, msgA, alpha16,
                                    startp, lg_src, edge_src, BT_bp, (const float*)0,
                                    msgB, (float*)0, E, 1);
  k_mpnn<<<egrid, 256, 0, stream>>>(x_nodes, x_edges, msgB, alpha16,
                                    startp, lg_src, edge_src, BT_bp, (const float*)0,
                                    msgA, (float*)0, E, 1);
  k_mpnn<<<egrid, 256, 0, stream>>>(x_nodes, x_edges, msgA, alpha16,
                                    startp, lg_src, edge_src, BT_bp, (const float*)0,
                                    msgB, (float*)0, E, 1);
  // dst-CSR (msgA region now dead; final msg in msgB)
  k_zero_int<<<ngrid, 256, 0, stream>>>(deg_d, N);
  k_hist<<<egrid256, 256, 0, stream>>>(edge_dst, deg_d, E);
  k_scan<<<1, 1024, 0, stream>>>(deg_d, start_d, cursor_d, N);
  k_fill<<<egrid256, 256, 0, stream>>>(edge_dst, (const int*)0, cursor_d, bucket_d, E);
  // output layer with fused m-gather: h = relu([x_node | gather(msgB)+alpha] @ Wo + b_o)
  k_mpnn<<<(N+63)/64, 256, 0, stream>>>(x_nodes, (const float*)0, msgB, alpha16,
                                        start_d, bucket_d, (const int*)0, BT_fo, b_o,
                                        (u16*)0, hbuf, N, 2);
  k_graph_mean<<<(G+3)/4, 256, 0, stream>>>(hbuf, gid, N, G, (float*)d_out);
}

// Round 5
// 1668.766 us; speedup vs baseline: 1.4694x; 1.1514x over previous
//
#include <hip/hip_runtime.h>
#include <stdint.h>

typedef unsigned short u16;
typedef __attribute__((ext_vector_type(8))) short bf16x8;
typedef __attribute__((ext_vector_type(4))) float f32x4;

#define HD 256
#define KX 320    // extended K: 64 (pad of [x|xe] or [x]) + 256

static __device__ __forceinline__ float b2f(u16 x){
  union{float f; unsigned u;} v; v.u = ((unsigned)x)<<16; return v.f;
}
static __device__ __forceinline__ u16 f2b(float f){
  union{float f; unsigned u;} v; v.f = f;
  unsigned r = v.u + 0x7fffu + ((v.u>>16)&1u);
  return (u16)(r>>16);
}
static __device__ __forceinline__ void acc8(float* g, uint4 ch){
  g[0] += b2f((u16)(ch.x)); g[1] += b2f((u16)(ch.x>>16));
  g[2] += b2f((u16)(ch.y)); g[3] += b2f((u16)(ch.y>>16));
  g[4] += b2f((u16)(ch.z)); g[5] += b2f((u16)(ch.z>>16));
  g[6] += b2f((u16)(ch.w)); g[7] += b2f((u16)(ch.w>>16));
}

// ---------------- zero int buffer ----------------
__global__ void k_zero_int(int* __restrict__ p, int n){
  int i = blockIdx.x*256 + threadIdx.x;
  if (i < n) p[i] = 0;
}

// ---------------- histogram: deg[key[i]]++ ----------------
__global__ void k_hist(const int* __restrict__ key, int* __restrict__ deg, int n){
  int i = blockIdx.x*256 + threadIdx.x;
  if (i < n) atomicAdd(&deg[key[i]], 1);
}

// ---------------- single-block exclusive scan ----------------
__global__ __launch_bounds__(1024) void k_scan(const int* __restrict__ deg, int* __restrict__ start,
                                               int* __restrict__ cursor, int n){
  __shared__ int sm[1024];
  const int t = threadIdx.x;
  const int chunk = (n + 1023) >> 10;
  const int lo = t*chunk, hi = min(lo+chunk, n);
  int s = 0;
  for (int i=lo;i<hi;i++) s += deg[i];
  sm[t] = s;
  __syncthreads();
  for (int ofs=1; ofs<1024; ofs<<=1){
    int v = (t>=ofs) ? sm[t-ofs] : 0;
    __syncthreads();
    sm[t] += v;
    __syncthreads();
  }
  int base = sm[t] - s;
  for (int i=lo;i<hi;i++){
    start[i] = base; cursor[i] = base;
    base += deg[i];
  }
  if (t == 1023) start[n] = sm[1023];
}

// ---------------- fill buckets ----------------
__global__ void k_fill(const int* __restrict__ key, const int* __restrict__ val,
                       int* __restrict__ cursor, int* __restrict__ bucket, int n){
  int i = blockIdx.x*256 + threadIdx.x;
  if (i >= n) return;
  int pos = atomicAdd(&cursor[key[i]], 1);
  bucket[pos] = val ? val[i] : i;
}

// ---------------- alpha16[v] = bf16( sum_{j} tree_m[bucket[j]] ) ----------------
__global__ void k_alpha_gather(const float* __restrict__ tree_m, const int* __restrict__ start,
                               const int* __restrict__ bucket, u16* __restrict__ alpha16, int N){
  int v = (int)(((long long)blockIdx.x*blockDim.x + threadIdx.x)>>6);
  int l = threadIdx.x & 63;
  if (v >= N) return;
  int s = start[v], e2 = start[v+1];
  float a0=0.f,a1=0.f,a2=0.f,a3=0.f;
  for (int j=s;j<e2;j++){
    float4 tv = *(const float4*)(tree_m + (long long)bucket[j]*HD + l*4);
    a0 += tv.x; a1 += tv.y; a2 += tv.z; a3 += tv.w;
  }
  ushort4 o; o.x=f2b(a0); o.y=f2b(a1); o.z=f2b(a2); o.w=f2b(a3);
  *(ushort4*)(alpha16 + (long long)v*HD + l*4) = o;
}

// ---------------- build concatenated transposed bf16 B matrices from fp32 W ----------------
__global__ void k_prep_B(const float* __restrict__ Wi, const float* __restrict__ Wh,
                         const float* __restrict__ Wo,
                         u16* __restrict__ BT_bp, u16* __restrict__ BT_fo){
  int n = blockIdx.x;
  for (int k = threadIdx.x; k < KX; k += blockDim.x){
    u16 bp = 0, fo = 0;
    if (k < 40) bp = f2b(Wi[k*HD + n]);
    else if (k >= 64) bp = f2b(Wh[(k-64)*HD + n]);
    if (k < 35) fo = f2b(Wo[k*HD + n]);
    else if (k >= 64) fo = f2b(Wo[(k-29)*HD + n]);
    BT_bp[n*KX + k] = bp;
    BT_fo[n*KX + k] = fo;
  }
}

// ---------------- segment pointers over sorted lg_dst ----------------
__global__ void k_segptr(const int* __restrict__ lg_dst, int L, int E, int* __restrict__ start){
  int e = blockIdx.x*256 + threadIdx.x;
  if (e > E) return;
  int lo = 0, hi = L;
  while (lo < hi){ int mid = (lo+hi)>>1; if (lg_dst[mid] < e) lo = mid+1; else hi = mid; }
  start[e] = lo;
}

// ---------------- fused MPNN GEMM, wave-per-16-rows, zero LDS, zero barriers ----------------
// Each wave: 16 rows (M) x 256 cols (N), K=320. Gather lands directly in MFMA
// A-fragment layout: lane (lr=l&15, lq=l>>4) owns row lr, channels lq*8+[0,8) per kstep.
// mode 0: A=[x_src|xe|0], ksteps 2, out16 = relu(x @ Wi)
// mode 1: A=[x_src|xe|0|lg_gather+alpha_src], ksteps 10, out16 = BP update
// mode 2: A=[x_node|0|dst_gather+alpha_row], ksteps 10, out32 = relu(..+b_o)
__global__ __launch_bounds__(256, 3) void k_mpnn(
    const float* __restrict__ xn, const float* __restrict__ xe,
    const u16* __restrict__ msg_in, const u16* __restrict__ alpha16,
    const int* __restrict__ seg, const int* __restrict__ keys,
    const int* __restrict__ esrc,
    const u16* __restrict__ BT, const float* __restrict__ bias,
    u16* __restrict__ out16, float* __restrict__ out32, int M, int mode)
{
  const int tid = threadIdx.x;
  const int wave = tid>>6, l = tid&63;
  const int lr = l&15, lq = l>>4;
  const long long m0 = (long long)blockIdx.x*64 + wave*16;
  const int row = (int)(m0 + lr);
  const bool rv = row < M;

  bf16x8 af[10];
  // ---- A frags ks0,1: raw features (fp32 -> bf16), channels k = ks*32 + lq*8 + i
  {
    int srcv = 0;
    if (rv) srcv = (mode==2) ? row : esrc[row];
    #pragma unroll
    for (int ks=0; ks<2; ks++){
      #pragma unroll
      for (int i=0;i<8;i++){
        int k = ks*32 + lq*8 + i;
        float v = 0.f;
        if (rv){
          if (k < 35) v = xn[(long long)srcv*35 + k];
          else if (k < 40 && mode != 2) v = xe[(long long)row*5 + (k-35)];
        }
        af[ks][i] = (short)f2b(v);
      }
    }
  }
  // ---- A frags ks2..9: fused segment gather + alpha, directly in fragment layout
  if (mode >= 1){
    float g[8][8];
    #pragma unroll
    for (int c=0;c<8;c++)
      #pragma unroll
      for (int i=0;i<8;i++) g[c][i] = 0.f;
    int an = 0;
    if (rv) an = (mode==1) ? esrc[row] : row;
    {
      const u16* ap = alpha16 + (long long)an*HD + lq*8;
      #pragma unroll
      for (int c=0;c<8;c++) acc8(g[c], *(const uint4*)(ap + c*32));
    }
    int s = rv ? seg[row] : 0;
    int e2 = rv ? seg[row+1] : 0;
    int j = s;
    int r2n = (j < e2) ? keys[j] : 0;
    while (j < e2){
      int r2 = r2n;
      j++;
      r2n = (j < e2) ? keys[j] : 0;
      const u16* mp = msg_in + (long long)r2*HD + lq*8;
      uint4 c0 = *(const uint4*)(mp + 0*32);
      uint4 c1 = *(const uint4*)(mp + 1*32);
      uint4 c2 = *(const uint4*)(mp + 2*32);
      uint4 c3 = *(const uint4*)(mp + 3*32);
      uint4 c4 = *(const uint4*)(mp + 4*32);
      uint4 c5 = *(const uint4*)(mp + 5*32);
      uint4 c6 = *(const uint4*)(mp + 6*32);
      uint4 c7 = *(const uint4*)(mp + 7*32);
      acc8(g[0], c0); acc8(g[1], c1); acc8(g[2], c2); acc8(g[3], c3);
      acc8(g[4], c4); acc8(g[5], c5); acc8(g[6], c6); acc8(g[7], c7);
    }
    #pragma unroll
    for (int c=0;c<8;c++)
      #pragma unroll
      for (int i=0;i<8;i++) af[2+c][i] = (short)f2b(g[c][i]);
  }

  // ---- MFMA: 16 N-tiles, B-frags straight from global (L2-resident 160 KB)
  f32x4 acc[16];
  #pragma unroll
  for (int nj=0;nj<16;nj++) acc[nj] = (f32x4){0.f,0.f,0.f,0.f};
  const u16* bbase = BT + (long long)lr*KX + lq*8;

#define KSTEP(ks) { \
    _Pragma("unroll") \
    for (int nj=0;nj<16;nj++){ \
      bf16x8 bf = *(const bf16x8*)(bbase + (long long)nj*16*KX + (ks)*32); \
      acc[nj] = __builtin_amdgcn_mfma_f32_16x16x32_bf16(af[ks], bf, acc[nj], 0,0,0); \
    } }
  KSTEP(0) KSTEP(1)
  if (mode != 0){
    KSTEP(2) KSTEP(3) KSTEP(4) KSTEP(5)
    KSTEP(6) KSTEP(7) KSTEP(8) KSTEP(9)
  }
#undef KSTEP

  // ---- epilogue: C/D layout col=lr, row=lq*4+reg
  #pragma unroll
  for (int reg=0; reg<4; reg++){
    long long gm = m0 + lq*4 + reg;
    if (gm < M){
      if (mode == 2){
        #pragma unroll
        for (int nj=0;nj<16;nj++){
          int col = nj*16 + lr;
          float v = acc[nj][reg] + bias[col];
          out32[gm*HD + col] = v > 0.f ? v : 0.f;
        }
      } else {
        #pragma unroll
        for (int nj=0;nj<16;nj++){
          int col = nj*16 + lr;
          float v = acc[nj][reg];
          out16[gm*HD + col] = f2b(v > 0.f ? v : 0.f);
        }
      }
    }
  }
}

// ---------------- graph mean (graph_ids sorted), fp32 in/out ----------------
__global__ void k_graph_mean(const float* __restrict__ h, const int* __restrict__ gid,
                             int N, int G, float* __restrict__ out){
  int g = (int)(((long long)blockIdx.x*blockDim.x + threadIdx.x)>>6);
  int l = threadIdx.x & 63;
  if (g >= G) return;
  int lo=0, hi=N;
  while (lo<hi){ int mid=(lo+hi)>>1; if (gid[mid] < g) lo=mid+1; else hi=mid; }
  int b = lo;
  hi = N;
  while (lo<hi){ int mid=(lo+hi)>>1; if (gid[mid] < g+1) lo=mid+1; else hi=mid; }
  int e2 = lo;
  float a0=0.f,a1=0.f,a2=0.f,a3=0.f;
  for (int v=b; v<e2; v++){
    float4 hv = *(const float4*)(h + (long long)v*HD + l*4);
    a0 += hv.x; a1 += hv.y; a2 += hv.z; a3 += hv.w;
  }
  int cnt = e2 - b; if (cnt < 1) cnt = 1;
  float inv = 1.0f/(float)cnt;
  float4 o; o.x=a0*inv; o.y=a1*inv; o.z=a2*inv; o.w=a3*inv;
  *(float4*)(out + (long long)g*HD + l*4) = o;
}

extern "C" void kernel_launch(void* const* d_in, const int* in_sizes, int n_in,
                              void* d_out, int out_size, void* d_ws, size_t ws_size,
                              hipStream_t stream){
  const float* x_nodes = (const float*)d_in[0];
  const float* x_edges = (const float*)d_in[1];
  const float* tree_m  = (const float*)d_in[2];
  const float* W_i     = (const float*)d_in[3];
  const float* W_h     = (const float*)d_in[4];
  const float* W_o     = (const float*)d_in[5];
  const float* b_o     = (const float*)d_in[6];
  const int* edge_src = (const int*)d_in[7];
  const int* edge_dst = (const int*)d_in[8];
  const int* lg_src   = (const int*)d_in[9];
  const int* lg_dst   = (const int*)d_in[10];
  const int* tgt      = (const int*)d_in[11];
  const int* teid     = (const int*)d_in[12];
  const int* gid      = (const int*)d_in[13];

  const int N = in_sizes[0]/35;
  const int E = in_sizes[1]/5;
  const int L = in_sizes[9];
  const int K = in_sizes[11];
  const int G = out_size/HD;

  // ---- workspace layout (~231.5 MB footprint, proven safe) ----
  char* wsb = (char*)d_ws;
  auto align256 = [](size_t x){ return (x + 255) & ~(size_t)255; };
  size_t oMsgA    = 0;
  size_t oMsgB    = oMsgA    + align256((size_t)E*HD*2);   // 102.4 MB
  size_t oAlpha16 = oMsgB    + align256((size_t)E*HD*2);   // 102.4 MB
  size_t oBTbp    = oAlpha16 + align256((size_t)N*HD*2);   // 25.6 MB
  size_t oBTfo    = oBTbp    + align256((size_t)256*KX*2); // 160 KB
  size_t oStart   = oBTfo    + align256((size_t)256*KX*2); // 160 KB

  u16*   msgA    = (u16*)(wsb + oMsgA);
  u16*   msgB    = (u16*)(wsb + oMsgB);
  u16*   alpha16 = (u16*)(wsb + oAlpha16);
  u16*   BT_bp   = (u16*)(wsb + oBTbp);
  u16*   BT_fo   = (u16*)(wsb + oBTfo);
  int*   startp  = (int*)(wsb + oStart);

  // tgt-CSR: in msgB region, consumed before BP iter1 writes msgB
  const size_t SLOT = 262144;
  int* deg_t    = (int*)(wsb + oMsgB + 0*SLOT);
  int* start_t  = (int*)(wsb + oMsgB + 1*SLOT);
  int* cursor_t = (int*)(wsb + oMsgB + 2*SLOT);
  int* bucket_t = (int*)(wsb + oMsgB + 3*SLOT);

  // dst-CSR + hbuf: in msgA region, used only after BP iter3 (msgA dead)
  float* hbuf   = (float*)(wsb + oMsgA);                   // 51.2 MB
  size_t oCsrD  = oMsgA + align256((size_t)N*HD*4) + 4096;
  int* deg_d    = (int*)(wsb + oCsrD + 0*SLOT);
  int* start_d  = (int*)(wsb + oCsrD + 1*SLOT);
  int* cursor_d = (int*)(wsb + oCsrD + 2*SLOT);
  int* bucket_d = (int*)(wsb + oCsrD + 3*SLOT);

  const int ngrid = (N+255)/256;
  const int egrid256 = (E+255)/256;
  const int kgrid256 = (K+255)/256;

  k_prep_B<<<256, 256, 0, stream>>>(W_i, W_h, W_o, BT_bp, BT_fo);
  k_segptr<<<(E+1+255)/256, 256, 0, stream>>>(lg_dst, L, E, startp);

  // tgt-CSR + alpha gather
  k_zero_int<<<ngrid, 256, 0, stream>>>(deg_t, N);
  k_hist<<<kgrid256, 256, 0, stream>>>(tgt, deg_t, K);
  k_scan<<<1, 1024, 0, stream>>>(deg_t, start_t, cursor_t, N);
  k_fill<<<kgrid256, 256, 0, stream>>>(tgt, teid, cursor_t, bucket_t, K);
  k_alpha_gather<<<(N+3)/4, 256, 0, stream>>>(tree_m, start_t, bucket_t, alpha16, N);

  const int egrid = (E+63)/64;
  // iter0: msgA = relu([x_src|xe] @ Wi)
  k_mpnn<<<egrid, 256, 0, stream>>>(x_nodes, x_edges, (const u16*)0, alpha16,
                                    startp, lg_src, edge_src, BT_bp, (const float*)0,
                                    msgA, (float*)0, E, 0);
  // BP iters: A -> B -> A -> B
  k_mpnn<<<egrid, 256, 0, stream>>>(x_nodes, x_edges, msgA, alpha16,
                                    startp, lg_src, edge_src, BT_bp, (const float*)0,
                                    msgB, (float*)0, E, 1);
  k_mpnn<<<egrid, 256, 0, stream>>>(x_nodes, x_edges, msgB, alpha16,
                                    startp, lg_src, edge_src, BT_bp, (const float*)0,
                                    msgA, (float*)0, E, 1);
  k_mpnn<<<egrid, 256, 0, stream>>>(x_nodes, x_edges, msgA, alpha16,
                                    startp, lg_src, edge_src, BT_bp, (const float*)0,
                                    msgB, (float*)0, E, 1);
  // dst-CSR (msgA dead; final msg in msgB)
  k_zero_int<<<ngrid, 256, 0, stream>>>(deg_d, N);
  k_hist<<<egrid256, 256, 0, stream>>>(edge_dst, deg_d, E);
  k_scan<<<1, 1024, 0, stream>>>(deg_d, start_d, cursor_d, N);
  k_fill<<<egrid256, 256, 0, stream>>>(edge_dst, (const int*)0, cursor_d, bucket_d, E);
  // output layer with fused m-gather
  k_mpnn<<<(N+63)/64, 256, 0, stream>>>(x_nodes, (const float*)0, msgB, alpha16,
                                        start_d, bucket_d, (const int*)0, BT_fo, b_o,
                                        (u16*)0, hbuf, N, 2);
  k_graph_mean<<<(G+3)/4, 256, 0, stream>>>(hbuf, gid, N, G, (float*)d_out);
}

// Round 6
// 1272.577 us; speedup vs baseline: 1.9269x; 1.3113x over previous
//
#include <hip/hip_runtime.h>
#include <stdint.h>

typedef unsigned short u16;
typedef __attribute__((ext_vector_type(8))) short bf16x8;
typedef __attribute__((ext_vector_type(4))) float f32x4;

#define HD 256
#define KX 320   // extended K: 64 (padded features) + 256
#define AST 328  // A_lds row stride in u16 (656 B: 16B-aligned, balanced banks)

static __device__ __forceinline__ float b2f(u16 x){
  union{float f; unsigned u;} v; v.u = ((unsigned)x)<<16; return v.f;
}
static __device__ __forceinline__ u16 f2b(float f){
  union{float f; unsigned u;} v; v.f = f;
  unsigned r = v.u + 0x7fffu + ((v.u>>16)&1u);
  return (u16)(r>>16);
}
static __device__ __forceinline__ void acc4(float* a, uint2 v){
  a[0] += b2f((u16)v.x); a[1] += b2f((u16)(v.x>>16));
  a[2] += b2f((u16)v.y); a[3] += b2f((u16)(v.y>>16));
}

// ---------------- zero int buffer ----------------
__global__ void k_zero_int(int* __restrict__ p, int n){
  int i = blockIdx.x*256 + threadIdx.x;
  if (i < n) p[i] = 0;
}

// ---------------- histogram ----------------
__global__ void k_hist(const int* __restrict__ key, int* __restrict__ deg, int n){
  int i = blockIdx.x*256 + threadIdx.x;
  if (i < n) atomicAdd(&deg[key[i]], 1);
}

// ---------------- single-block exclusive scan ----------------
__global__ __launch_bounds__(1024) void k_scan(const int* __restrict__ deg, int* __restrict__ start,
                                               int* __restrict__ cursor, int n){
  __shared__ int sm[1024];
  const int t = threadIdx.x;
  const int chunk = (n + 1023) >> 10;
  const int lo = t*chunk, hi = min(lo+chunk, n);
  int s = 0;
  for (int i=lo;i<hi;i++) s += deg[i];
  sm[t] = s;
  __syncthreads();
  for (int ofs=1; ofs<1024; ofs<<=1){
    int v = (t>=ofs) ? sm[t-ofs] : 0;
    __syncthreads();
    sm[t] += v;
    __syncthreads();
  }
  int base = sm[t] - s;
  for (int i=lo;i<hi;i++){
    start[i] = base; cursor[i] = base;
    base += deg[i];
  }
  if (t == 1023) start[n] = sm[1023];
}

// ---------------- fill buckets ----------------
__global__ void k_fill(const int* __restrict__ key, const int* __restrict__ val,
                       int* __restrict__ cursor, int* __restrict__ bucket, int n){
  int i = blockIdx.x*256 + threadIdx.x;
  if (i >= n) return;
  int pos = atomicAdd(&cursor[key[i]], 1);
  bucket[pos] = val ? val[i] : i;
}

// ---------------- alpha16[v] = bf16( sum_{j} tree_m[bucket[j]] ) ----------------
__global__ void k_alpha_gather(const float* __restrict__ tree_m, const int* __restrict__ start,
                               const int* __restrict__ bucket, u16* __restrict__ alpha16, int N){
  int v = (int)(((long long)blockIdx.x*blockDim.x + threadIdx.x)>>6);
  int l = threadIdx.x & 63;
  if (v >= N) return;
  int s = start[v], e2 = start[v+1];
  float a0=0.f,a1=0.f,a2=0.f,a3=0.f;
  for (int j=s;j<e2;j++){
    float4 tv = *(const float4*)(tree_m + (long long)bucket[j]*HD + l*4);
    a0 += tv.x; a1 += tv.y; a2 += tv.z; a3 += tv.w;
  }
  ushort4 o; o.x=f2b(a0); o.y=f2b(a1); o.z=f2b(a2); o.w=f2b(a3);
  *(ushort4*)(alpha16 + (long long)v*HD + l*4) = o;
}

// ---------------- frag-major B prep ----------------
// BTf[(ks*16+nj)*512 + l*8 + i] = W[k][n], n = nj*16+(l&15), k = ks*32+(l>>4)*8+i.
// One B-frag load is then 64 lanes x 16 B fully contiguous.
__global__ void k_prep_B(const float* __restrict__ Wi, const float* __restrict__ Wh,
                         const float* __restrict__ Wo,
                         u16* __restrict__ BTf_bp, u16* __restrict__ BTf_fo){
  int g = blockIdx.x*256 + threadIdx.x;   // 81920 total
  if (g >= 81920) return;
  int i = g & 7;
  int l = (g>>3) & 63;
  int t = g >> 9;                // 0..159
  int nj = t & 15, ks = t >> 4;  // ks 0..9
  int n = nj*16 + (l & 15);
  int k = ks*32 + (l>>4)*8 + i;
  float bp = 0.f, fo = 0.f;
  if (k < 40) bp = Wi[k*HD + n];
  else if (k >= 64) bp = Wh[(k-64)*HD + n];
  if (k < 35) fo = Wo[k*HD + n];
  else if (k >= 64) fo = Wo[(k-29)*HD + n];
  BTf_bp[g] = f2b(bp);
  BTf_fo[g] = f2b(fo);
}

// ---------------- segment pointers over sorted lg_dst ----------------
__global__ void k_segptr(const int* __restrict__ lg_dst, int L, int E, int* __restrict__ start){
  int e = blockIdx.x*256 + threadIdx.x;
  if (e > E) return;
  int lo = 0, hi = L;
  while (lo < hi){ int mid = (lo+hi)>>1; if (lg_dst[mid] < e) lo = mid+1; else hi = mid; }
  start[e] = lo;
}

// ---------------- fused MPNN GEMM, wave-per-16-rows ----------------
// A staged in wave-private LDS slice with coalesced loads; B frag-major coalesced.
// mode 0: A=[x_src|xe|0], ksteps 2; mode 1: +lg_gather+alpha_src, ksteps 10 (out16)
// mode 2: A=[x_node|0|dst_gather+alpha_row], ksteps 10 (out32, +bias)
__global__ __launch_bounds__(256, 3) void k_mpnn(
    const float* __restrict__ xn, const float* __restrict__ xe,
    const u16* __restrict__ msg_in, const u16* __restrict__ alpha16,
    const int* __restrict__ seg, const int* __restrict__ keys,
    const int* __restrict__ esrc,
    const u16* __restrict__ BTf, const float* __restrict__ bias,
    u16* __restrict__ out16, float* __restrict__ out32, int M, int Lkeys, int mode)
{
  __shared__ u16 A_lds[4][16][AST];   // 41,984 B -> 3 blocks/CU
  const int tid = threadIdx.x;
  const int wave = tid>>6, l = tid&63;
  const int lr = l&15, lq = l>>4;
  const int m0 = blockIdx.x*64 + wave*16;
  u16* Aw = &A_lds[wave][0][0];

  // per-lane row metadata (all lq groups redundantly compute; __shfl(x, r) reads lane r)
  const int rowl = m0 + lr;
  const bool rvl = rowl < M;
  int srcl = 0, sl = 0, el = 0;
  if (rvl){
    srcl = (mode==2) ? rowl : esrc[rowl];
    if (mode != 0){ sl = seg[rowl]; el = seg[rowl+1]; }
  }

  // ---- stage features cols [0,64): coalesced per-row loads
  for (int r=0; r<16; r++){
    int sv = __shfl(srcl, r);
    int rw = m0 + r;
    float v = 0.f;
    if (rw < M){
      if (l < 35) v = xn[(long long)sv*35 + l];
      else if (l < 40 && mode != 2) v = xe[(long long)rw*5 + (l-35)];
    }
    Aw[r*AST + l] = f2b(v);
  }

  // ---- stage gathered cols [64,320): coalesced 512-B row loads, keys broadcast
  if (mode != 0){
    const int base = __shfl(sl, 0);
    int kc0 = (base + l      < Lkeys) ? keys[base + l]      : 0;
    int kc1 = (base + 64 + l < Lkeys) ? keys[base + 64 + l] : 0;
    auto keyat = [&](int j)->int{
      int idx = j - base;
      if (idx < 64)  return __shfl(kc0, idx);
      if (idx < 128) return __shfl(kc1, idx-64);
      return keys[j];
    };
    const u16* msg_l = msg_in + l*4;
    for (int r=0; r<16; r++){
      int s  = __shfl(sl, r);
      int e  = __shfl(el, r);
      int an = __shfl(srcl, r);
      float a[4];
      { uint2 av = *(const uint2*)(alpha16 + (long long)an*HD + l*4);
        a[0]=b2f((u16)av.x); a[1]=b2f((u16)(av.x>>16));
        a[2]=b2f((u16)av.y); a[3]=b2f((u16)(av.y>>16)); }
      int j = s;
      for (; j+4 <= e; j+=4){
        int q0 = keyat(j), q1 = keyat(j+1), q2 = keyat(j+2), q3 = keyat(j+3);
        uint2 v0 = *(const uint2*)(msg_l + (long long)q0*HD);
        uint2 v1 = *(const uint2*)(msg_l + (long long)q1*HD);
        uint2 v2 = *(const uint2*)(msg_l + (long long)q2*HD);
        uint2 v3 = *(const uint2*)(msg_l + (long long)q3*HD);
        acc4(a, v0); acc4(a, v1); acc4(a, v2); acc4(a, v3);
      }
      for (; j < e; j++){
        int q = keyat(j);
        uint2 v = *(const uint2*)(msg_l + (long long)q*HD);
        acc4(a, v);
      }
      ushort4 o; o.x=f2b(a[0]); o.y=f2b(a[1]); o.z=f2b(a[2]); o.w=f2b(a[3]);
      *(ushort4*)&Aw[r*AST + 64 + l*4] = o;
    }
  }

  // ---- A-frags from LDS (wave-private; no barrier needed)
  const u16* Ar = &A_lds[wave][lr][0];
  bf16x8 af[10];
  af[0] = *(const bf16x8*)(Ar + 0*32 + lq*8);
  af[1] = *(const bf16x8*)(Ar + 1*32 + lq*8);
  if (mode != 0){
    #pragma unroll
    for (int ks=2; ks<10; ks++) af[ks] = *(const bf16x8*)(Ar + ks*32 + lq*8);
  }

  // ---- MFMA: frag-major B, fully coalesced loads
  f32x4 acc[16];
  #pragma unroll
  for (int nj=0;nj<16;nj++) acc[nj] = (f32x4){0.f,0.f,0.f,0.f};
  const u16* bb = BTf + l*8;

#define KSTEP(ks) { \
    _Pragma("unroll") \
    for (int nj=0;nj<16;nj++){ \
      bf16x8 bf = *(const bf16x8*)(bb + ((ks)*16+nj)*512); \
      acc[nj] = __builtin_amdgcn_mfma_f32_16x16x32_bf16(af[ks], bf, acc[nj], 0,0,0); \
    } }
  KSTEP(0) KSTEP(1)
  if (mode != 0){
    KSTEP(2) KSTEP(3) KSTEP(4) KSTEP(5)
    KSTEP(6) KSTEP(7) KSTEP(8) KSTEP(9)
  }
#undef KSTEP

  // ---- epilogue: C/D layout col=lr, row=lq*4+reg
  #pragma unroll
  for (int reg=0; reg<4; reg++){
    int gm = m0 + lq*4 + reg;
    if (gm < M){
      if (mode == 2){
        #pragma unroll
        for (int nj=0;nj<16;nj++){
          int col = nj*16 + lr;
          float v = acc[nj][reg] + bias[col];
          out32[(long long)gm*HD + col] = v > 0.f ? v : 0.f;
        }
      } else {
        #pragma unroll
        for (int nj=0;nj<16;nj++){
          int col = nj*16 + lr;
          float v = acc[nj][reg];
          out16[(long long)gm*HD + col] = f2b(v > 0.f ? v : 0.f);
        }
      }
    }
  }
}

// ---------------- graph mean (graph_ids sorted), fp32 in/out ----------------
__global__ void k_graph_mean(const float* __restrict__ h, const int* __restrict__ gid,
                             int N, int G, float* __restrict__ out){
  int g = (int)(((long long)blockIdx.x*blockDim.x + threadIdx.x)>>6);
  int l = threadIdx.x & 63;
  if (g >= G) return;
  int lo=0, hi=N;
  while (lo<hi){ int mid=(lo+hi)>>1; if (gid[mid] < g) lo=mid+1; else hi=mid; }
  int b = lo;
  hi = N;
  while (lo<hi){ int mid=(lo+hi)>>1; if (gid[mid] < g+1) lo=mid+1; else hi=mid; }
  int e2 = lo;
  float a0=0.f,a1=0.f,a2=0.f,a3=0.f;
  for (int v=b; v<e2; v++){
    float4 hv = *(const float4*)(h + (long long)v*HD + l*4);
    a0 += hv.x; a1 += hv.y; a2 += hv.z; a3 += hv.w;
  }
  int cnt = e2 - b; if (cnt < 1) cnt = 1;
  float inv = 1.0f/(float)cnt;
  float4 o; o.x=a0*inv; o.y=a1*inv; o.z=a2*inv; o.w=a3*inv;
  *(float4*)(out + (long long)g*HD + l*4) = o;
}

extern "C" void kernel_launch(void* const* d_in, const int* in_sizes, int n_in,
                              void* d_out, int out_size, void* d_ws, size_t ws_size,
                              hipStream_t stream){
  const float* x_nodes = (const float*)d_in[0];
  const float* x_edges = (const float*)d_in[1];
  const float* tree_m  = (const float*)d_in[2];
  const float* W_i     = (const float*)d_in[3];
  const float* W_h     = (const float*)d_in[4];
  const float* W_o     = (const float*)d_in[5];
  const float* b_o     = (const float*)d_in[6];
  const int* edge_src = (const int*)d_in[7];
  const int* edge_dst = (const int*)d_in[8];
  const int* lg_src   = (const int*)d_in[9];
  const int* lg_dst   = (const int*)d_in[10];
  const int* tgt      = (const int*)d_in[11];
  const int* teid     = (const int*)d_in[12];
  const int* gid      = (const int*)d_in[13];

  const int N = in_sizes[0]/35;
  const int E = in_sizes[1]/5;
  const int L = in_sizes[9];
  const int K = in_sizes[11];
  const int G = out_size/HD;

  // ---- workspace layout (~231.5 MB footprint, proven safe) ----
  char* wsb = (char*)d_ws;
  auto align256 = [](size_t x){ return (x + 255) & ~(size_t)255; };
  size_t oMsgA    = 0;
  size_t oMsgB    = oMsgA    + align256((size_t)E*HD*2);   // 102.4 MB
  size_t oAlpha16 = oMsgB    + align256((size_t)E*HD*2);   // 102.4 MB
  size_t oBTbp    = oAlpha16 + align256((size_t)N*HD*2);   // 25.6 MB
  size_t oBTfo    = oBTbp    + align256((size_t)81920*2);  // 160 KB
  size_t oStart   = oBTfo    + align256((size_t)81920*2);  // 160 KB

  u16*   msgA    = (u16*)(wsb + oMsgA);
  u16*   msgB    = (u16*)(wsb + oMsgB);
  u16*   alpha16 = (u16*)(wsb + oAlpha16);
  u16*   BTf_bp  = (u16*)(wsb + oBTbp);
  u16*   BTf_fo  = (u16*)(wsb + oBTfo);
  int*   startp  = (int*)(wsb + oStart);

  // tgt-CSR: in msgB region, consumed before BP iter1 writes msgB
  const size_t SLOT = 262144;
  int* deg_t    = (int*)(wsb + oMsgB + 0*SLOT);
  int* start_t  = (int*)(wsb + oMsgB + 1*SLOT);
  int* cursor_t = (int*)(wsb + oMsgB + 2*SLOT);
  int* bucket_t = (int*)(wsb + oMsgB + 3*SLOT);

  // dst-CSR + hbuf: in msgA region, used only after BP iter3 (msgA dead)
  float* hbuf   = (float*)(wsb + oMsgA);                   // 51.2 MB
  size_t oCsrD  = oMsgA + align256((size_t)N*HD*4) + 4096;
  int* deg_d    = (int*)(wsb + oCsrD + 0*SLOT);
  int* start_d  = (int*)(wsb + oCsrD + 1*SLOT);
  int* cursor_d = (int*)(wsb + oCsrD + 2*SLOT);
  int* bucket_d = (int*)(wsb + oCsrD + 3*SLOT);

  const int ngrid = (N+255)/256;
  const int egrid256 = (E+255)/256;
  const int kgrid256 = (K+255)/256;

  k_prep_B<<<320, 256, 0, stream>>>(W_i, W_h, W_o, BTf_bp, BTf_fo);
  k_segptr<<<(E+1+255)/256, 256, 0, stream>>>(lg_dst, L, E, startp);

  // tgt-CSR + alpha gather
  k_zero_int<<<ngrid, 256, 0, stream>>>(deg_t, N);
  k_hist<<<kgrid256, 256, 0, stream>>>(tgt, deg_t, K);
  k_scan<<<1, 1024, 0, stream>>>(deg_t, start_t, cursor_t, N);
  k_fill<<<kgrid256, 256, 0, stream>>>(tgt, teid, cursor_t, bucket_t, K);
  k_alpha_gather<<<(N+3)/4, 256, 0, stream>>>(tree_m, start_t, bucket_t, alpha16, N);

  const int egrid = (E+63)/64;
  // iter0: msgA = relu([x_src|xe] @ Wi)
  k_mpnn<<<egrid, 256, 0, stream>>>(x_nodes, x_edges, (const u16*)0, alpha16,
                                    startp, lg_src, edge_src, BTf_bp, (const float*)0,
                                    msgA, (float*)0, E, 0, 0);
  // BP iters: A -> B -> A -> B
  k_mpnn<<<egrid, 256, 0, stream>>>(x_nodes, x_edges, msgA, alpha16,
                                    startp, lg_src, edge_src, BTf_bp, (const float*)0,
                                    msgB, (float*)0, E, L, 1);
  k_mpnn<<<egrid, 256, 0, stream>>>(x_nodes, x_edges, msgB, alpha16,
                                    startp, lg_src, edge_src, BTf_bp, (const float*)0,
                                    msgA, (float*)0, E, L, 1);
  k_mpnn<<<egrid, 256, 0, stream>>>(x_nodes, x_edges, msgA, alpha16,
                                    startp, lg_src, edge_src, BTf_bp, (const float*)0,
                                    msgB, (float*)0, E, L, 1);
  // dst-CSR (msgA dead; final msg in msgB)
  k_zero_int<<<ngrid, 256, 0, stream>>>(deg_d, N);
  k_hist<<<egrid256, 256, 0, stream>>>(edge_dst, deg_d, E);
  k_scan<<<1, 1024, 0, stream>>>(deg_d, start_d, cursor_d, N);
  k_fill<<<egrid256, 256, 0, stream>>>(edge_dst, (const int*)0, cursor_d, bucket_d, E);
  // output layer with fused m-gather
  k_mpnn<<<(N+63)/64, 256, 0, stream>>>(x_nodes, (const float*)0, msgB, alpha16,
                                        start_d, bucket_d, (const int*)0, BTf_fo, b_o,
                                        (u16*)0, hbuf, N, E, 2);
  k_graph_mean<<<(G+3)/4, 256, 0, stream>>>(hbuf, gid, N, G, (float*)d_out);
}